// Round 1
// baseline (231.933 us; speedup 1.0000x reference)
//
#include <hip/hip_runtime.h>
#include <hip/hip_bf16.h>

typedef __bf16 bf16;
typedef __bf16 bf16x4 __attribute__((ext_vector_type(4)));
typedef __bf16 bf16x8 __attribute__((ext_vector_type(8)));
typedef float  f32x4  __attribute__((ext_vector_type(4)));

static __device__ __forceinline__ f32x4 mfma16(bf16x8 a, bf16x8 b, f32x4 c) {
  return __builtin_amdgcn_mfma_f32_16x16x32_bf16(a, b, c, 0, 0, 0);
}

static __device__ __forceinline__ void gload_lds16(const bf16* g, bf16* l) {
  __builtin_amdgcn_global_load_lds(
      (const __attribute__((address_space(1))) void*)g,
      (__attribute__((address_space(3))) void*)l, 16, 0, 0);
}

// ---------------- fp32 -> bf16 weight cast ----------------
__global__ __launch_bounds__(256) void cvt_bf16_kernel(const float* __restrict__ in,
                                                       bf16* __restrict__ out, int n4) {
  int i = blockIdx.x * 256 + threadIdx.x;
  if (i >= n4) return;
  float4 v = ((const float4*)in)[i];
  bf16x4 o = { (bf16)v.x, (bf16)v.y, (bf16)v.z, (bf16)v.w };
  *(bf16x4*)(out + 4ll * i) = o;
}

// ---------------- GroupNorm -> xnT (b, t, c) bf16 ----------------
__global__ __launch_bounds__(256) void gn_kernel(const float* __restrict__ x,
                                                 const float* __restrict__ w,
                                                 const float* __restrict__ bias,
                                                 bf16* __restrict__ xnT) {
  int b = blockIdx.x >> 5, g = blockIdx.x & 31;
  const float* xb = x + ((size_t)b * 1024 + g * 32) * 1024;   // 32 ch x 1024 t
  int tid = threadIdx.x;
  float s = 0.f, sq = 0.f;
  const float4* x4 = (const float4*)xb;
  for (int i = tid; i < 8192; i += 256) {
    float4 v = x4[i];
    s  += v.x + v.y + v.z + v.w;
    sq += v.x * v.x + v.y * v.y + v.z * v.z + v.w * v.w;
  }
#pragma unroll
  for (int off = 32; off; off >>= 1) { s += __shfl_down(s, off); sq += __shfl_down(sq, off); }
  __shared__ float red[8];
  int wid = tid >> 6;
  if ((tid & 63) == 0) { red[wid] = s; red[4 + wid] = sq; }
  __syncthreads();
  s  = red[0] + red[1] + red[2] + red[3];
  sq = red[4] + red[5] + red[6] + red[7];
  float mean = s * (1.f / 32768.f);
  float var  = sq * (1.f / 32768.f) - mean * mean;
  float rstd = rsqrtf(var + 1e-5f);

  __shared__ bf16 tile[32][36];
  int c = tid >> 3, q = tid & 7;               // c: 0..31, q: 0..7
  float wc = w[g * 32 + c] * rstd;
  float fb = bias[g * 32 + c] - mean * wc;
  for (int t0 = 0; t0 < 1024; t0 += 32) {
    float4 v = *(const float4*)(xb + (size_t)c * 1024 + t0 + q * 4);
    tile[q * 4 + 0][c] = (bf16)(v.x * wc + fb);
    tile[q * 4 + 1][c] = (bf16)(v.y * wc + fb);
    tile[q * 4 + 2][c] = (bf16)(v.z * wc + fb);
    tile[q * 4 + 3][c] = (bf16)(v.w * wc + fb);
    __syncthreads();
    // write role: row t = c (0..31), 4 channels per thread
    *(bf16x4*)&xnT[((size_t)b * 1024 + t0 + c) * 1024 + g * 32 + q * 4] =
        *(bf16x4*)&tile[c][q * 4];
    __syncthreads();
  }
}

// ---------------- 128x128x32 bf16 MFMA GEMM ----------------
// C[z][m][n] = sum_k A[z][m][k] * Bw[n][k]   (both K-contiguous)
// MODE 0: qkv epilogue (bias, q/k scale, split write qkT / vC)
// MODE 1: proj epilogue (bias + residual, transposed fp32 write)
template <int MODE>
__global__ __launch_bounds__(256) void gemm_kernel(
    const bf16* __restrict__ A, const bf16* __restrict__ Bw,
    const float* __restrict__ bias,
    bf16* __restrict__ qkT, bf16* __restrict__ vC,
    const float* __restrict__ xres, float* __restrict__ out) {
  __shared__ bf16 At[128 * 32];
  __shared__ bf16 Bt[128 * 32];
  int tid = threadIdx.x;
  int wid = tid >> 6, lane = tid & 63;
  int l15 = lane & 15, l4 = lane >> 4;
  int wm = wid >> 1, wn = wid & 1;
  int z = blockIdx.z;
  int m0 = blockIdx.y * 128, n0 = blockIdx.x * 128;
  const bf16* Ab = A + (size_t)z * 1024 * 1024 + (size_t)m0 * 1024;
  const bf16* Bb = Bw + (size_t)n0 * 1024;

  f32x4 acc[4][4] = {};

  for (int k0 = 0; k0 < 1024; k0 += 32) {
#pragma unroll
    for (int j = 0; j < 2; ++j) {
      int slot = j * 256 + tid;
      int row  = slot >> 2;
      int ck   = (slot & 3) ^ ((row >> 1) & 3);   // pre-swizzled source chunk
      gload_lds16(Ab + (size_t)row * 1024 + k0 + ck * 8, At + (size_t)(j * 256 + wid * 64) * 8);
      gload_lds16(Bb + (size_t)row * 1024 + k0 + ck * 8, Bt + (size_t)(j * 256 + wid * 64) * 8);
    }
    __syncthreads();
    bf16x8 af[4], bfr[4];
#pragma unroll
    for (int mi = 0; mi < 4; ++mi) {
      int row = wm * 64 + mi * 16 + l15;
      int ck  = l4 ^ ((row >> 1) & 3);
      af[mi] = *(const bf16x8*)(At + row * 32 + ck * 8);
    }
#pragma unroll
    for (int nf = 0; nf < 4; ++nf) {
      int row = wn * 64 + nf * 16 + l15;
      int ck  = l4 ^ ((row >> 1) & 3);
      bfr[nf] = *(const bf16x8*)(Bt + row * 32 + ck * 8);
    }
#pragma unroll
    for (int mi = 0; mi < 4; ++mi)
#pragma unroll
      for (int nf = 0; nf < 4; ++nf)
        acc[mi][nf] = mfma16(af[mi], bfr[nf], acc[mi][nf]);
    __syncthreads();
  }

  if (MODE == 0) {
    const float scale = 0.35355339059327373f;   // 64^-0.25
#pragma unroll
    for (int nf = 0; nf < 4; ++nf) {
      int ob = n0 + wn * 64 + nf * 16;          // frag col base (16-aligned)
      int h = ob / 192, oin = ob % 192;         // uniform per frag
      float bv = bias[ob + l15];
#pragma unroll
      for (int mi = 0; mi < 4; ++mi) {
        int tb = m0 + wm * 64 + mi * 16 + l4 * 4;
        f32x4 v = acc[mi][nf];
        if (oin < 128) {                        // q or k -> qkT[b][t][h*128 + oin]
#pragma unroll
          for (int i = 0; i < 4; ++i)
            qkT[((size_t)z * 1024 + tb + i) * 2048 + h * 128 + oin + l15] =
                (bf16)((v[i] + bv) * scale);
        } else {                                // v -> vC[(b*16+h)][c][t]
          bf16x4 st = { (bf16)(v[0] + bv), (bf16)(v[1] + bv),
                        (bf16)(v[2] + bv), (bf16)(v[3] + bv) };
          *(bf16x4*)&vC[(((size_t)z * 16 + h) * 64 + (oin - 128 + l15)) * 1024 + tb] = st;
        }
      }
    }
  } else {
#pragma unroll
    for (int nf = 0; nf < 4; ++nf) {
      int o = n0 + wn * 64 + nf * 16 + l15;
      float bv = bias[o];
#pragma unroll
      for (int mi = 0; mi < 4; ++mi) {
        int tb = m0 + wm * 64 + mi * 16 + l4 * 4;
        size_t base = ((size_t)z * 1024 + o) * 1024 + tb;
        float4 xr = *(const float4*)(xres + base);
        f32x4 v = acc[mi][nf];
        float4 ov = { xr.x + v[0] + bv, xr.y + v[1] + bv,
                      xr.z + v[2] + bv, xr.w + v[3] + bv };
        *(float4*)(out + base) = ov;
      }
    }
  }
}

// ---------------- flash attention: 64 heads, S=1024, D=64 ----------------
__global__ __launch_bounds__(256) void attn_kernel(const bf16* __restrict__ qkT,
                                                   const bf16* __restrict__ vC,
                                                   bf16* __restrict__ aT) {
  int head = blockIdx.y;
  int b = head >> 4, h = head & 15;
  int t0 = blockIdx.x * 64;
  int tid = threadIdx.x, wid = tid >> 6, lane = tid & 63;
  int l15 = lane & 15, l4 = lane >> 4;
  int trow = t0 + wid * 16;

  __shared__ bf16 P[4][16][136];                // per-wave P tile, padded rows
  bf16(*Pw)[136] = P[wid];

  const bf16* qrow = qkT + ((size_t)b * 1024 + trow + l15) * 2048 + h * 128;
  bf16x8 qf[2];
#pragma unroll
  for (int kb = 0; kb < 2; ++kb) qf[kb] = *(const bf16x8*)(qrow + kb * 32 + l4 * 8);

  const bf16* kbase = qkT + (size_t)b * 1024 * 2048 + h * 128 + 64;
  const bf16* vbase = vC + (size_t)(b * 16 + h) * 64 * 1024;

  float m_run[4], l_run[4];
#pragma unroll
  for (int i = 0; i < 4; ++i) { m_run[i] = -1e30f; l_run[i] = 0.f; }
  f32x4 oacc[4] = {};

  for (int s0 = 0; s0 < 1024; s0 += 128) {
    f32x4 sf[8];
#pragma unroll
    for (int nf = 0; nf < 8; ++nf) {
      sf[nf] = (f32x4){0.f, 0.f, 0.f, 0.f};
      const bf16* kr = kbase + (size_t)(s0 + nf * 16 + l15) * 2048;
#pragma unroll
      for (int kb = 0; kb < 2; ++kb) {
        bf16x8 kf = *(const bf16x8*)(kr + kb * 32 + l4 * 8);
        sf[nf] = mfma16(qf[kb], kf, sf[nf]);
      }
    }
    float mb[4], sb[4];
#pragma unroll
    for (int i = 0; i < 4; ++i) {
      float mm = sf[0][i];
#pragma unroll
      for (int nf = 1; nf < 8; ++nf) mm = fmaxf(mm, sf[nf][i]);
      mb[i] = mm;
    }
#pragma unroll
    for (int off = 1; off < 16; off <<= 1)
#pragma unroll
      for (int i = 0; i < 4; ++i) mb[i] = fmaxf(mb[i], __shfl_xor(mb[i], off));
    float corr[4];
#pragma unroll
    for (int i = 0; i < 4; ++i) {
      float mn = fmaxf(m_run[i], mb[i]);
      corr[i] = __expf(m_run[i] - mn);
      m_run[i] = mn;
      sb[i] = 0.f;
    }
#pragma unroll
    for (int nf = 0; nf < 8; ++nf) {
#pragma unroll
      for (int i = 0; i < 4; ++i) {
        float p = __expf(sf[nf][i] - m_run[i]);
        sb[i] += p;
        Pw[l4 * 4 + i][nf * 16 + l15] = (bf16)p;
      }
    }
#pragma unroll
    for (int off = 1; off < 16; off <<= 1)
#pragma unroll
      for (int i = 0; i < 4; ++i) sb[i] += __shfl_xor(sb[i], off);
#pragma unroll
    for (int i = 0; i < 4; ++i) l_run[i] = l_run[i] * corr[i] + sb[i];
#pragma unroll
    for (int cf = 0; cf < 4; ++cf)
#pragma unroll
      for (int i = 0; i < 4; ++i) oacc[cf][i] *= corr[i];
#pragma unroll
    for (int kb = 0; kb < 4; ++kb) {
      bf16x8 pf = *(const bf16x8*)&Pw[l15][kb * 32 + l4 * 8];
#pragma unroll
      for (int cf = 0; cf < 4; ++cf) {
        bf16x8 vf = *(const bf16x8*)(vbase + (size_t)(cf * 16 + l15) * 1024 + s0 + kb * 32 + l4 * 8);
        oacc[cf] = mfma16(pf, vf, oacc[cf]);
      }
    }
  }
#pragma unroll
  for (int cf = 0; cf < 4; ++cf) {
    int cc = h * 64 + cf * 16 + l15;
#pragma unroll
    for (int i = 0; i < 4; ++i) {
      int t = trow + l4 * 4 + i;
      aT[((size_t)b * 1024 + t) * 1024 + cc] = (bf16)(oacc[cf][i] / l_run[i]);
    }
  }
}

extern "C" void kernel_launch(void* const* d_in, const int* in_sizes, int n_in,
                              void* d_out, int out_size, void* d_ws, size_t ws_size,
                              hipStream_t stream) {
  const float* x      = (const float*)d_in[0];
  const float* gw     = (const float*)d_in[1];
  const float* gb     = (const float*)d_in[2];
  const float* qkv_w  = (const float*)d_in[3];
  const float* qkv_b  = (const float*)d_in[4];
  const float* proj_w = (const float*)d_in[5];
  const float* proj_b = (const float*)d_in[6];
  float* out = (float*)d_out;

  char* ws = (char*)d_ws;
  bf16* wq_bf = (bf16*)(ws);                          //  6 MB: 3072x1024
  bf16* wp_bf = (bf16*)(ws + 6ll  * 1024 * 1024);     //  2 MB: 1024x1024
  bf16* xnT   = (bf16*)(ws + 8ll  * 1024 * 1024);     //  8 MB: [4][1024][1024]
  bf16* qkT   = (bf16*)(ws + 16ll * 1024 * 1024);     // 16 MB: [4][1024][2048] (q|k per head)
  bf16* vC    = (bf16*)(ws + 32ll * 1024 * 1024);     //  8 MB: [64][64][1024]
  bf16* aT    = (bf16*)(ws + 40ll * 1024 * 1024);     //  8 MB: [4][1024][1024]

  cvt_bf16_kernel<<<dim3(3072), dim3(256), 0, stream>>>(qkv_w, wq_bf, 3072 * 1024 / 4);
  cvt_bf16_kernel<<<dim3(1024), dim3(256), 0, stream>>>(proj_w, wp_bf, 1024 * 1024 / 4);
  gn_kernel<<<dim3(128), dim3(256), 0, stream>>>(x, gw, gb, xnT);
  gemm_kernel<0><<<dim3(24, 8, 4), dim3(256), 0, stream>>>(xnT, wq_bf, qkv_b, qkT, vC, nullptr, nullptr);
  attn_kernel<<<dim3(16, 64), dim3(256), 0, stream>>>(qkT, vC, aT);
  gemm_kernel<1><<<dim3(8, 8, 4), dim3(256), 0, stream>>>(aT, wp_bf, proj_b, nullptr, nullptr, x, out);
}

// Round 2
// 149.423 us; speedup vs baseline: 1.5522x; 1.5522x over previous
//
#include <hip/hip_runtime.h>
#include <hip/hip_bf16.h>

typedef __bf16 bf16;
typedef __bf16 bf16x4 __attribute__((ext_vector_type(4)));
typedef __bf16 bf16x8 __attribute__((ext_vector_type(8)));
typedef float  f32x4  __attribute__((ext_vector_type(4)));

static __device__ __forceinline__ f32x4 mfma16(bf16x8 a, bf16x8 b, f32x4 c) {
  return __builtin_amdgcn_mfma_f32_16x16x32_bf16(a, b, c, 0, 0, 0);
}

static __device__ __forceinline__ void gload_lds16(const bf16* g, bf16* l) {
  __builtin_amdgcn_global_load_lds(
      (const __attribute__((address_space(1))) void*)g,
      (__attribute__((address_space(3))) void*)l, 16, 0, 0);
}

// ---------------- fp32 -> bf16 weight cast ----------------
__global__ __launch_bounds__(256) void cvt_bf16_kernel(const float* __restrict__ in,
                                                       bf16* __restrict__ out, int n4) {
  int i = blockIdx.x * 256 + threadIdx.x;
  if (i >= n4) return;
  float4 v = ((const float4*)in)[i];
  bf16x4 o = { (bf16)v.x, (bf16)v.y, (bf16)v.z, (bf16)v.w };
  *(bf16x4*)(out + 4ll * i) = o;
}

// ---------------- GroupNorm -> xnT (b, t, c) bf16 ----------------
__global__ __launch_bounds__(256) void gn_kernel(const float* __restrict__ x,
                                                 const float* __restrict__ w,
                                                 const float* __restrict__ bias,
                                                 bf16* __restrict__ xnT) {
  int b = blockIdx.x >> 5, g = blockIdx.x & 31;
  const float* xb = x + ((size_t)b * 1024 + g * 32) * 1024;   // 32 ch x 1024 t
  int tid = threadIdx.x;
  float s = 0.f, sq = 0.f;
  const float4* x4 = (const float4*)xb;
  for (int i = tid; i < 8192; i += 256) {
    float4 v = x4[i];
    s  += v.x + v.y + v.z + v.w;
    sq += v.x * v.x + v.y * v.y + v.z * v.z + v.w * v.w;
  }
#pragma unroll
  for (int off = 32; off; off >>= 1) { s += __shfl_down(s, off); sq += __shfl_down(sq, off); }
  __shared__ float red[8];
  int wid = tid >> 6;
  if ((tid & 63) == 0) { red[wid] = s; red[4 + wid] = sq; }
  __syncthreads();
  s  = red[0] + red[1] + red[2] + red[3];
  sq = red[4] + red[5] + red[6] + red[7];
  float mean = s * (1.f / 32768.f);
  float var  = sq * (1.f / 32768.f) - mean * mean;
  float rstd = rsqrtf(var + 1e-5f);

  __shared__ bf16 tile[32][36];
  int c = tid >> 3, q = tid & 7;               // c: 0..31, q: 0..7
  float wc = w[g * 32 + c] * rstd;
  float fb = bias[g * 32 + c] - mean * wc;
  for (int t0 = 0; t0 < 1024; t0 += 32) {
    float4 v = *(const float4*)(xb + (size_t)c * 1024 + t0 + q * 4);
    tile[q * 4 + 0][c] = (bf16)(v.x * wc + fb);
    tile[q * 4 + 1][c] = (bf16)(v.y * wc + fb);
    tile[q * 4 + 2][c] = (bf16)(v.z * wc + fb);
    tile[q * 4 + 3][c] = (bf16)(v.w * wc + fb);
    __syncthreads();
    *(bf16x4*)&xnT[((size_t)b * 1024 + t0 + c) * 1024 + g * 32 + q * 4] =
        *(bf16x4*)&tile[c][q * 4];
    __syncthreads();
  }
}

// ---------------- 128x128x32 bf16 MFMA GEMM ----------------
template <int MODE>
__global__ __launch_bounds__(256) void gemm_kernel(
    const bf16* __restrict__ A, const bf16* __restrict__ Bw,
    const float* __restrict__ bias,
    bf16* __restrict__ qkT, bf16* __restrict__ vC,
    const float* __restrict__ xres, float* __restrict__ out) {
  __shared__ bf16 At[128 * 32];
  __shared__ bf16 Bt[128 * 32];
  int tid = threadIdx.x;
  int wid = tid >> 6, lane = tid & 63;
  int l15 = lane & 15, l4 = lane >> 4;
  int wm = wid >> 1, wn = wid & 1;
  int z = blockIdx.z;
  int m0 = blockIdx.y * 128, n0 = blockIdx.x * 128;
  const bf16* Ab = A + (size_t)z * 1024 * 1024 + (size_t)m0 * 1024;
  const bf16* Bb = Bw + (size_t)n0 * 1024;

  f32x4 acc[4][4] = {};

  for (int k0 = 0; k0 < 1024; k0 += 32) {
#pragma unroll
    for (int j = 0; j < 2; ++j) {
      int slot = j * 256 + tid;
      int row  = slot >> 2;
      int ck   = (slot & 3) ^ ((row >> 1) & 3);   // pre-swizzled source chunk
      gload_lds16(Ab + (size_t)row * 1024 + k0 + ck * 8, At + (size_t)(j * 256 + wid * 64) * 8);
      gload_lds16(Bb + (size_t)row * 1024 + k0 + ck * 8, Bt + (size_t)(j * 256 + wid * 64) * 8);
    }
    __syncthreads();
    bf16x8 af[4], bfr[4];
#pragma unroll
    for (int mi = 0; mi < 4; ++mi) {
      int row = wm * 64 + mi * 16 + l15;
      int ck  = l4 ^ ((row >> 1) & 3);
      af[mi] = *(const bf16x8*)(At + row * 32 + ck * 8);
    }
#pragma unroll
    for (int nf = 0; nf < 4; ++nf) {
      int row = wn * 64 + nf * 16 + l15;
      int ck  = l4 ^ ((row >> 1) & 3);
      bfr[nf] = *(const bf16x8*)(Bt + row * 32 + ck * 8);
    }
#pragma unroll
    for (int mi = 0; mi < 4; ++mi)
#pragma unroll
      for (int nf = 0; nf < 4; ++nf)
        acc[mi][nf] = mfma16(af[mi], bfr[nf], acc[mi][nf]);
    __syncthreads();
  }

  if (MODE == 0) {
    const float scale = 0.35355339059327373f;   // 64^-0.25
#pragma unroll
    for (int nf = 0; nf < 4; ++nf) {
      int ob = n0 + wn * 64 + nf * 16;          // frag col base (16-aligned)
      int h = ob / 192, oin = ob % 192;         // uniform per frag
      float bv = bias[ob + l15];
#pragma unroll
      for (int mi = 0; mi < 4; ++mi) {
        int tb = m0 + wm * 64 + mi * 16 + l4 * 4;
        f32x4 v = acc[mi][nf];
        if (oin < 128) {                        // q or k -> qkT[b][t][h*128 + oin]
#pragma unroll
          for (int i = 0; i < 4; ++i)
            qkT[((size_t)z * 1024 + tb + i) * 2048 + h * 128 + oin + l15] =
                (bf16)((v[i] + bv) * scale);
        } else {                                // v -> vC[(b*16+h)][c][t]
          bf16x4 st = { (bf16)(v[0] + bv), (bf16)(v[1] + bv),
                        (bf16)(v[2] + bv), (bf16)(v[3] + bv) };
          *(bf16x4*)&vC[(((size_t)z * 16 + h) * 64 + (oin - 128 + l15)) * 1024 + tb] = st;
        }
      }
    }
  } else {
#pragma unroll
    for (int nf = 0; nf < 4; ++nf) {
      int o = n0 + wn * 64 + nf * 16 + l15;
      float bv = bias[o];
#pragma unroll
      for (int mi = 0; mi < 4; ++mi) {
        int tb = m0 + wm * 64 + mi * 16 + l4 * 4;
        size_t base = ((size_t)z * 1024 + o) * 1024 + tb;
        float4 xr = *(const float4*)(xres + base);
        f32x4 v = acc[mi][nf];
        float4 ov = { xr.x + v[0] + bv, xr.y + v[1] + bv,
                      xr.z + v[2] + bv, xr.w + v[3] + bv };
        *(float4*)(out + base) = ov;
      }
    }
  }
}

// ---------------- flash attention v2: LDS-staged, double-buffered ----------------
// 64 heads (b*16+h), S=1024, D=64. Block = 4 waves x 16 t-rows = 64 rows.
// K/V staged in LDS (SBLK=64) via global_load_lds, XOR-swizzled, double-buffered.
__global__ __launch_bounds__(256, 4) void attn_kernel(const bf16* __restrict__ qkT,
                                                      const bf16* __restrict__ vC,
                                                      bf16* __restrict__ aT) {
  __shared__ __align__(16) bf16 Kt[2][64 * 64];   // [buf][s][d] swizzled, 16 KB
  __shared__ __align__(16) bf16 Vt[2][64 * 64];   // [buf][c][s] swizzled, 16 KB
  __shared__ __align__(16) bf16 Pt[4][16 * 64];   // per-wave P, swizzled, 8 KB

  int id = blockIdx.x;
  int sid = (id & 7) * 128 + (id >> 3);           // bijective XCD swizzle (1024 % 8 == 0)
  int head = sid >> 4, tblk = sid & 15;
  int b = head >> 4, h = head & 15;
  int t0 = tblk * 64;
  int tid = threadIdx.x, wid = tid >> 6, lane = tid & 63;
  int l15 = lane & 15, l4 = lane >> 4;
  int trow = t0 + wid * 16;

  const bf16* kbase = qkT + (size_t)b * 1024 * 2048 + h * 128 + 64;
  const bf16* vbase = vC + (size_t)(b * 16 + h) * 64 * 1024;
  char* Pw = (char*)Pt[wid];

  // Q fragments (read once)
  const bf16* qrow = qkT + ((size_t)b * 1024 + trow + l15) * 2048 + h * 128;
  bf16x8 qf[2];
#pragma unroll
  for (int kb = 0; kb < 2; ++kb) qf[kb] = *(const bf16x8*)(qrow + kb * 32 + l4 * 8);

  // stage tile st into buffer buf (K: rows=s, V: rows=c; 128B rows, XOR-swizzled
  // via pre-swizzled global source since global_load_lds writes linearly)
  int rl = lane >> 3;                              // row within 8-row group
  int scol = (((lane & 7) * 16) ^ (rl << 4)) >> 1; // element col, swizzle folded in
  auto stage = [&](int buf, int st) {
    int s0 = st * 64;
#pragma unroll
    for (int j = 0; j < 2; ++j) {
      int g = j * 4 + wid;                         // 8-row group, wave-uniform
      int r = g * 8 + rl;
      gload_lds16(kbase + (size_t)(s0 + r) * 2048 + scol, &Kt[buf][g * 512]);
      gload_lds16(vbase + (size_t)r * 1024 + s0 + scol, &Vt[buf][g * 512]);
    }
  };

  float m_run[4], l_run[4];
#pragma unroll
  for (int i = 0; i < 4; ++i) { m_run[i] = -1e30f; l_run[i] = 0.f; }
  f32x4 oacc[4] = {};

  stage(0, 0);
  __syncthreads();

  int rsw = (l15 & 7) << 4;                        // read-side XOR (row = ..+l15)
  for (int st = 0; st < 16; ++st) {
    int cur = st & 1;
    if (st < 15) stage(cur ^ 1, st + 1);

    // ---- QK^T: 8 MFMA ----
    const char* Kb = (const char*)Kt[cur];
    f32x4 sf[4];
#pragma unroll
    for (int nf = 0; nf < 4; ++nf) {
      sf[nf] = (f32x4){0.f, 0.f, 0.f, 0.f};
      int rr = nf * 16 + l15;
#pragma unroll
      for (int kb = 0; kb < 2; ++kb) {
        bf16x8 kf = *(const bf16x8*)(Kb + rr * 128 + ((kb * 64 + l4 * 16) ^ rsw));
        sf[nf] = mfma16(qf[kb], kf, sf[nf]);
      }
    }

    // ---- online softmax ----
    float mb[4], sb[4];
#pragma unroll
    for (int i = 0; i < 4; ++i) {
      float mm = sf[0][i];
#pragma unroll
      for (int nf = 1; nf < 4; ++nf) mm = fmaxf(mm, sf[nf][i]);
      mb[i] = mm;
    }
#pragma unroll
    for (int off = 1; off < 16; off <<= 1)
#pragma unroll
      for (int i = 0; i < 4; ++i) mb[i] = fmaxf(mb[i], __shfl_xor(mb[i], off));
    float corr[4];
#pragma unroll
    for (int i = 0; i < 4; ++i) {
      float mn = fmaxf(m_run[i], mb[i]);
      corr[i] = __expf(m_run[i] - mn);
      m_run[i] = mn;
      sb[i] = 0.f;
    }
#pragma unroll
    for (int nf = 0; nf < 4; ++nf) {
#pragma unroll
      for (int i = 0; i < 4; ++i) {
        float p = __expf(sf[nf][i] - m_run[i]);
        sb[i] += p;
        int pr = l4 * 4 + i;
        *(bf16*)(Pw + pr * 128 + ((nf * 32 + l15 * 2) ^ ((pr & 7) << 4))) = (bf16)p;
      }
    }
#pragma unroll
    for (int off = 1; off < 16; off <<= 1)
#pragma unroll
      for (int i = 0; i < 4; ++i) sb[i] += __shfl_xor(sb[i], off);
#pragma unroll
    for (int i = 0; i < 4; ++i) l_run[i] = l_run[i] * corr[i] + sb[i];
#pragma unroll
    for (int cf = 0; cf < 4; ++cf)
#pragma unroll
      for (int i = 0; i < 4; ++i) oacc[cf][i] *= corr[i];

    // ---- PV: 8 MFMA ----
    const char* Vb = (const char*)Vt[cur];
#pragma unroll
    for (int kb = 0; kb < 2; ++kb) {
      bf16x8 pf = *(const bf16x8*)(Pw + l15 * 128 + ((kb * 64 + l4 * 16) ^ rsw));
#pragma unroll
      for (int cf = 0; cf < 4; ++cf) {
        int rr = cf * 16 + l15;
        bf16x8 vf = *(const bf16x8*)(Vb + rr * 128 + ((kb * 64 + l4 * 16) ^ rsw));
        oacc[cf] = mfma16(pf, vf, oacc[cf]);
      }
    }
    __syncthreads();   // drains vmcnt(0): next tile staged & this tile's readers done
  }

#pragma unroll
  for (int cf = 0; cf < 4; ++cf) {
    int cc = h * 64 + cf * 16 + l15;
#pragma unroll
    for (int i = 0; i < 4; ++i) {
      int t = trow + l4 * 4 + i;
      aT[((size_t)b * 1024 + t) * 1024 + cc] = (bf16)(oacc[cf][i] / l_run[i]);
    }
  }
}

extern "C" void kernel_launch(void* const* d_in, const int* in_sizes, int n_in,
                              void* d_out, int out_size, void* d_ws, size_t ws_size,
                              hipStream_t stream) {
  const float* x      = (const float*)d_in[0];
  const float* gw     = (const float*)d_in[1];
  const float* gb     = (const float*)d_in[2];
  const float* qkv_w  = (const float*)d_in[3];
  const float* qkv_b  = (const float*)d_in[4];
  const float* proj_w = (const float*)d_in[5];
  const float* proj_b = (const float*)d_in[6];
  float* out = (float*)d_out;

  char* ws = (char*)d_ws;
  bf16* wq_bf = (bf16*)(ws);                          //  6 MB: 3072x1024
  bf16* wp_bf = (bf16*)(ws + 6ll  * 1024 * 1024);     //  2 MB: 1024x1024
  bf16* xnT   = (bf16*)(ws + 8ll  * 1024 * 1024);     //  8 MB: [4][1024][1024]
  bf16* qkT   = (bf16*)(ws + 16ll * 1024 * 1024);     // 16 MB: [4][1024][2048] (q|k per head)
  bf16* vC    = (bf16*)(ws + 32ll * 1024 * 1024);     //  8 MB: [64][64][1024]
  bf16* aT    = (bf16*)(ws + 40ll * 1024 * 1024);     //  8 MB: [4][1024][1024]

  cvt_bf16_kernel<<<dim3(3072), dim3(256), 0, stream>>>(qkv_w, wq_bf, 3072 * 1024 / 4);
  cvt_bf16_kernel<<<dim3(1024), dim3(256), 0, stream>>>(proj_w, wp_bf, 1024 * 1024 / 4);
  gn_kernel<<<dim3(128), dim3(256), 0, stream>>>(x, gw, gb, xnT);
  gemm_kernel<0><<<dim3(24, 8, 4), dim3(256), 0, stream>>>(xnT, wq_bf, qkv_b, qkT, vC, nullptr, nullptr);
  attn_kernel<<<dim3(1024), dim3(256), 0, stream>>>(qkT, vC, aT);
  gemm_kernel<1><<<dim3(8, 8, 4), dim3(256), 0, stream>>>(aT, wp_bf, proj_b, nullptr, nullptr, x, out);
}

// Round 3
// 130.429 us; speedup vs baseline: 1.7782x; 1.1456x over previous
//
#include <hip/hip_runtime.h>
#include <hip/hip_bf16.h>

typedef __bf16 bf16;
typedef __bf16 bf16x2 __attribute__((ext_vector_type(2)));
typedef __bf16 bf16x4 __attribute__((ext_vector_type(4)));
typedef __bf16 bf16x8 __attribute__((ext_vector_type(8)));
typedef float  f32x4  __attribute__((ext_vector_type(4)));

static __device__ __forceinline__ f32x4 mfma16(bf16x8 a, bf16x8 b, f32x4 c) {
  return __builtin_amdgcn_mfma_f32_16x16x32_bf16(a, b, c, 0, 0, 0);
}

static __device__ __forceinline__ void gload_lds16(const bf16* g, bf16* l) {
  __builtin_amdgcn_global_load_lds(
      (const __attribute__((address_space(1))) void*)g,
      (__attribute__((address_space(3))) void*)l, 16, 0, 0);
}

// ---------------- fp32 -> bf16 weight cast ----------------
__global__ __launch_bounds__(256) void cvt_bf16_kernel(const float* __restrict__ in,
                                                       bf16* __restrict__ out, int n4) {
  int i = blockIdx.x * 256 + threadIdx.x;
  if (i >= n4) return;
  float4 v = ((const float4*)in)[i];
  bf16x4 o = { (bf16)v.x, (bf16)v.y, (bf16)v.z, (bf16)v.w };
  *(bf16x4*)(out + 4ll * i) = o;
}

// ---------------- GroupNorm -> xnT (b, t, c) bf16 ----------------
__global__ __launch_bounds__(256) void gn_kernel(const float* __restrict__ x,
                                                 const float* __restrict__ w,
                                                 const float* __restrict__ bias,
                                                 bf16* __restrict__ xnT) {
  int b = blockIdx.x >> 5, g = blockIdx.x & 31;
  const float* xb = x + ((size_t)b * 1024 + g * 32) * 1024;   // 32 ch x 1024 t
  int tid = threadIdx.x;
  float s = 0.f, sq = 0.f;
  const float4* x4 = (const float4*)xb;
  for (int i = tid; i < 8192; i += 256) {
    float4 v = x4[i];
    s  += v.x + v.y + v.z + v.w;
    sq += v.x * v.x + v.y * v.y + v.z * v.z + v.w * v.w;
  }
#pragma unroll
  for (int off = 32; off; off >>= 1) { s += __shfl_down(s, off); sq += __shfl_down(sq, off); }
  __shared__ float red[8];
  int wid = tid >> 6;
  if ((tid & 63) == 0) { red[wid] = s; red[4 + wid] = sq; }
  __syncthreads();
  s  = red[0] + red[1] + red[2] + red[3];
  sq = red[4] + red[5] + red[6] + red[7];
  float mean = s * (1.f / 32768.f);
  float var  = sq * (1.f / 32768.f) - mean * mean;
  float rstd = rsqrtf(var + 1e-5f);

  __shared__ bf16 tile[32][36];
  int c = tid >> 3, q = tid & 7;               // c: 0..31, q: 0..7
  float wc = w[g * 32 + c] * rstd;
  float fb = bias[g * 32 + c] - mean * wc;
  for (int t0 = 0; t0 < 1024; t0 += 32) {
    float4 v = *(const float4*)(xb + (size_t)c * 1024 + t0 + q * 4);
    tile[q * 4 + 0][c] = (bf16)(v.x * wc + fb);
    tile[q * 4 + 1][c] = (bf16)(v.y * wc + fb);
    tile[q * 4 + 2][c] = (bf16)(v.z * wc + fb);
    tile[q * 4 + 3][c] = (bf16)(v.w * wc + fb);
    __syncthreads();
    *(bf16x4*)&xnT[((size_t)b * 1024 + t0 + c) * 1024 + g * 32 + q * 4] =
        *(bf16x4*)&tile[c][q * 4];
    __syncthreads();
  }
}

// ---------------- 128x128x32 bf16 MFMA GEMM ----------------
template <int MODE>
__global__ __launch_bounds__(256) void gemm_kernel(
    const bf16* __restrict__ A, const bf16* __restrict__ Bw,
    const float* __restrict__ bias,
    bf16* __restrict__ qkT, bf16* __restrict__ vC,
    const float* __restrict__ xres, float* __restrict__ out) {
  __shared__ bf16 At[128 * 32];
  __shared__ bf16 Bt[128 * 32];
  int tid = threadIdx.x;
  int wid = tid >> 6, lane = tid & 63;
  int l15 = lane & 15, l4 = lane >> 4;
  int wm = wid >> 1, wn = wid & 1;
  int z = blockIdx.z;
  int m0 = blockIdx.y * 128, n0 = blockIdx.x * 128;
  const bf16* Ab = A + (size_t)z * 1024 * 1024 + (size_t)m0 * 1024;
  const bf16* Bb = Bw + (size_t)n0 * 1024;

  f32x4 acc[4][4] = {};

  for (int k0 = 0; k0 < 1024; k0 += 32) {
#pragma unroll
    for (int j = 0; j < 2; ++j) {
      int slot = j * 256 + tid;
      int row  = slot >> 2;
      int ck   = (slot & 3) ^ ((row >> 1) & 3);   // pre-swizzled source chunk
      gload_lds16(Ab + (size_t)row * 1024 + k0 + ck * 8, At + (size_t)(j * 256 + wid * 64) * 8);
      gload_lds16(Bb + (size_t)row * 1024 + k0 + ck * 8, Bt + (size_t)(j * 256 + wid * 64) * 8);
    }
    __syncthreads();
    bf16x8 af[4], bfr[4];
#pragma unroll
    for (int mi = 0; mi < 4; ++mi) {
      int row = wm * 64 + mi * 16 + l15;
      int ck  = l4 ^ ((row >> 1) & 3);
      af[mi] = *(const bf16x8*)(At + row * 32 + ck * 8);
    }
#pragma unroll
    for (int nf = 0; nf < 4; ++nf) {
      int row = wn * 64 + nf * 16 + l15;
      int ck  = l4 ^ ((row >> 1) & 3);
      bfr[nf] = *(const bf16x8*)(Bt + row * 32 + ck * 8);
    }
#pragma unroll
    for (int mi = 0; mi < 4; ++mi)
#pragma unroll
      for (int nf = 0; nf < 4; ++nf)
        acc[mi][nf] = mfma16(af[mi], bfr[nf], acc[mi][nf]);
    __syncthreads();
  }

  if (MODE == 0) {
    const float scale = 0.35355339059327373f;   // 64^-0.25
#pragma unroll
    for (int nf = 0; nf < 4; ++nf) {
      int ob = n0 + wn * 64 + nf * 16;          // frag col base (16-aligned)
      int h = ob / 192, oin = ob % 192;         // uniform per frag
      float bv = bias[ob + l15];
#pragma unroll
      for (int mi = 0; mi < 4; ++mi) {
        int tb = m0 + wm * 64 + mi * 16 + l4 * 4;
        f32x4 v = acc[mi][nf];
        if (oin < 128) {                        // q or k -> qkT[b][t][h*128 + oin]
#pragma unroll
          for (int i = 0; i < 4; ++i)
            qkT[((size_t)z * 1024 + tb + i) * 2048 + h * 128 + oin + l15] =
                (bf16)((v[i] + bv) * scale);
        } else {                                // v -> vC[(b*16+h)][c][t]
          bf16x4 st = { (bf16)(v[0] + bv), (bf16)(v[1] + bv),
                        (bf16)(v[2] + bv), (bf16)(v[3] + bv) };
          *(bf16x4*)&vC[(((size_t)z * 16 + h) * 64 + (oin - 128 + l15)) * 1024 + tb] = st;
        }
      }
    }
  } else {
#pragma unroll
    for (int nf = 0; nf < 4; ++nf) {
      int o = n0 + wn * 64 + nf * 16 + l15;
      float bv = bias[o];
#pragma unroll
      for (int mi = 0; mi < 4; ++mi) {
        int tb = m0 + wm * 64 + mi * 16 + l4 * 4;
        size_t base = ((size_t)z * 1024 + o) * 1024 + tb;
        float4 xr = *(const float4*)(xres + base);
        f32x4 v = acc[mi][nf];
        float4 ov = { xr.x + v[0] + bv, xr.y + v[1] + bv,
                      xr.z + v[2] + bv, xr.w + v[3] + bv };
        *(float4*)(out + base) = ov;
      }
    }
  }
}

// ---------------- flash attention v3: swapped-operand softmax ----------------
// QK^T computed as mfma(K,Q) -> S^T[s][t]: each lane owns ONE t (=l15) and 16
// lane-local s values -> row-reduce = 15 local fmax + 2 shfl_xor. PV swapped
// too (mfma(V,P) -> O^T[c][t]) so corr/l_run are lane-local scalars.
__global__ __launch_bounds__(256, 4) void attn_kernel(const bf16* __restrict__ qkT,
                                                      const bf16* __restrict__ vC,
                                                      bf16* __restrict__ aT) {
  __shared__ __align__(16) bf16 Kt[2][64 * 64];   // [buf][s][d] swizzled, 16 KB
  __shared__ __align__(16) bf16 Vt[2][64 * 64];   // [buf][c][s] swizzled, 16 KB
  __shared__ __align__(16) bf16 Pt[4][16 * 64];   // per-wave P[t][s], swizzled, 8 KB

  int id = blockIdx.x;
  int sid = (id & 7) * 128 + (id >> 3);           // bijective XCD swizzle (1024 % 8 == 0)
  int head = sid >> 4, tblk = sid & 15;
  int b = head >> 4, h = head & 15;
  int t0 = tblk * 64;
  int tid = threadIdx.x, wid = tid >> 6, lane = tid & 63;
  int l15 = lane & 15, l4 = lane >> 4;
  int trow = t0 + wid * 16;

  const bf16* kbase = qkT + (size_t)b * 1024 * 2048 + h * 128 + 64;
  const bf16* vbase = vC + (size_t)(b * 16 + h) * 64 * 1024;
  char* Pw = (char*)Pt[wid];
  int rsw = (l15 & 7) << 4;                        // row-XOR for P (row = l15)
  char* PwRow = Pw + l15 * 128;

  // Q fragments (read once); B-operand layout: row=t=l15, k=l4*8+j
  const bf16* qrow = qkT + ((size_t)b * 1024 + trow + l15) * 2048 + h * 128;
  bf16x8 qf[2];
#pragma unroll
  for (int kb = 0; kb < 2; ++kb) qf[kb] = *(const bf16x8*)(qrow + kb * 32 + l4 * 8);

  // stage tile st into buffer buf (pre-swizzled global source, linear LDS dest)
  int rl = lane >> 3;                              // row within 8-row group
  int scol = (((lane & 7) * 16) ^ (rl << 4)) >> 1; // element col, swizzle folded in
  auto stage = [&](int buf, int st) {
    int s0 = st * 64;
#pragma unroll
    for (int j = 0; j < 2; ++j) {
      int g = j * 4 + wid;                         // 8-row group, wave-uniform
      int r = g * 8 + rl;
      gload_lds16(kbase + (size_t)(s0 + r) * 2048 + scol, &Kt[buf][g * 512]);
      gload_lds16(vbase + (size_t)r * 1024 + s0 + scol, &Vt[buf][g * 512]);
    }
  };

  float m_run = -1e30f, l_run = 0.f;
  f32x4 oacc[4] = {};                              // O^T[c][t]: col t=l15, rows c

  stage(0, 0);
  __syncthreads();

  for (int st = 0; st < 16; ++st) {
    int cur = st & 1;
    if (st < 15) stage(cur ^ 1, st + 1);

    // ---- QK^T swapped: S^T[s][t], 8 MFMA ----
    const char* Kb = (const char*)Kt[cur];
    f32x4 sf[4];
#pragma unroll
    for (int nf = 0; nf < 4; ++nf) sf[nf] = (f32x4){0.f, 0.f, 0.f, 0.f};
    __builtin_amdgcn_s_setprio(1);
#pragma unroll
    for (int nf = 0; nf < 4; ++nf) {
      int rr = nf * 16 + l15;                      // A-frag row = s
#pragma unroll
      for (int kb = 0; kb < 2; ++kb) {
        bf16x8 kf = *(const bf16x8*)(Kb + rr * 128 + ((kb * 64 + l4 * 16) ^ rsw));
        sf[nf] = mfma16(kf, qf[kb], sf[nf]);
      }
    }
    __builtin_amdgcn_s_setprio(0);

    // ---- online softmax: lane owns t=l15, s = nf*16 + l4*4 + i ----
    float mb;
    {
      float a0 = fmaxf(fmaxf(sf[0][0], sf[0][1]), fmaxf(sf[0][2], sf[0][3]));
      float a1 = fmaxf(fmaxf(sf[1][0], sf[1][1]), fmaxf(sf[1][2], sf[1][3]));
      float a2 = fmaxf(fmaxf(sf[2][0], sf[2][1]), fmaxf(sf[2][2], sf[2][3]));
      float a3 = fmaxf(fmaxf(sf[3][0], sf[3][1]), fmaxf(sf[3][2], sf[3][3]));
      mb = fmaxf(fmaxf(a0, a1), fmaxf(a2, a3));
    }
    mb = fmaxf(mb, __shfl_xor(mb, 16));
    mb = fmaxf(mb, __shfl_xor(mb, 32));
    if (!__all(mb - m_run <= 8.f)) {               // T13 defer-max
      float mn = fmaxf(m_run, mb);
      float corr = __expf(m_run - mn);
      m_run = mn;
      l_run *= corr;
#pragma unroll
      for (int cf = 0; cf < 4; ++cf)
#pragma unroll
        for (int i = 0; i < 4; ++i) oacc[cf][i] *= corr;
    }
    float sb = 0.f;
#pragma unroll
    for (int nf = 0; nf < 4; ++nf) {
      float p0 = __expf(sf[nf][0] - m_run), p1 = __expf(sf[nf][1] - m_run);
      float p2 = __expf(sf[nf][2] - m_run), p3 = __expf(sf[nf][3] - m_run);
      sb += (p0 + p1) + (p2 + p3);
      int off = nf * 32 + l4 * 8;
      *(bf16x2*)(PwRow + (off ^ rsw))       = (bf16x2){ (bf16)p0, (bf16)p1 };
      *(bf16x2*)(PwRow + ((off + 4) ^ rsw)) = (bf16x2){ (bf16)p2, (bf16)p3 };
    }
    sb += __shfl_xor(sb, 16);
    sb += __shfl_xor(sb, 32);
    l_run += sb;

    // ---- PV swapped: O^T += V * P, 8 MFMA ----
    const char* Vb = (const char*)Vt[cur];
    __builtin_amdgcn_s_setprio(1);
#pragma unroll
    for (int kb = 0; kb < 2; ++kb) {
      bf16x8 pf = *(const bf16x8*)(Pw + l15 * 128 + ((kb * 64 + l4 * 16) ^ rsw));
#pragma unroll
      for (int cf = 0; cf < 4; ++cf) {
        int rr = cf * 16 + l15;                    // A-frag row = c
        bf16x8 vf = *(const bf16x8*)(Vb + rr * 128 + ((kb * 64 + l4 * 16) ^ rsw));
        oacc[cf] = mfma16(vf, pf, oacc[cf]);
      }
    }
    __builtin_amdgcn_s_setprio(0);
    __syncthreads();   // drains vmcnt(0): next tile staged & this tile's readers done
  }

  float rdiv = 1.f / l_run;                        // lane-local (t = l15)
  int t = trow + l15;
#pragma unroll
  for (int cf = 0; cf < 4; ++cf) {
    bf16x4 ov = { (bf16)(oacc[cf][0] * rdiv), (bf16)(oacc[cf][1] * rdiv),
                  (bf16)(oacc[cf][2] * rdiv), (bf16)(oacc[cf][3] * rdiv) };
    *(bf16x4*)&aT[((size_t)b * 1024 + t) * 1024 + h * 64 + cf * 16 + l4 * 4] = ov;
  }
}

extern "C" void kernel_launch(void* const* d_in, const int* in_sizes, int n_in,
                              void* d_out, int out_size, void* d_ws, size_t ws_size,
                              hipStream_t stream) {
  const float* x      = (const float*)d_in[0];
  const float* gw     = (const float*)d_in[1];
  const float* gb     = (const float*)d_in[2];
  const float* qkv_w  = (const float*)d_in[3];
  const float* qkv_b  = (const float*)d_in[4];
  const float* proj_w = (const float*)d_in[5];
  const float* proj_b = (const float*)d_in[6];
  float* out = (float*)d_out;

  char* ws = (char*)d_ws;
  bf16* wq_bf = (bf16*)(ws);                          //  6 MB: 3072x1024
  bf16* wp_bf = (bf16*)(ws + 6ll  * 1024 * 1024);     //  2 MB: 1024x1024
  bf16* xnT   = (bf16*)(ws + 8ll  * 1024 * 1024);     //  8 MB: [4][1024][1024]
  bf16* qkT   = (bf16*)(ws + 16ll * 1024 * 1024);     // 16 MB: [4][1024][2048] (q|k per head)
  bf16* vC    = (bf16*)(ws + 32ll * 1024 * 1024);     //  8 MB: [64][64][1024]
  bf16* aT    = (bf16*)(ws + 40ll * 1024 * 1024);     //  8 MB: [4][1024][1024]

  cvt_bf16_kernel<<<dim3(3072), dim3(256), 0, stream>>>(qkv_w, wq_bf, 3072 * 1024 / 4);
  cvt_bf16_kernel<<<dim3(1024), dim3(256), 0, stream>>>(proj_w, wp_bf, 1024 * 1024 / 4);
  gn_kernel<<<dim3(128), dim3(256), 0, stream>>>(x, gw, gb, xnT);
  gemm_kernel<0><<<dim3(24, 8, 4), dim3(256), 0, stream>>>(xnT, wq_bf, qkv_b, qkT, vC, nullptr, nullptr);
  attn_kernel<<<dim3(1024), dim3(256), 0, stream>>>(qkT, vC, aT);
  gemm_kernel<1><<<dim3(8, 8, 4), dim3(256), 0, stream>>>(aT, wp_bf, proj_b, nullptr, nullptr, x, out);
}